// Round 8
// baseline (1499.610 us; speedup 1.0000x reference)
//
#include <hip/hip_runtime.h>

typedef float f32x4 __attribute__((ext_vector_type(4)));

constexpr int N_NODES = 50000;
constexpr int F_IN    = 512;
constexpr int F_HID   = 256;
constexpr int F_OUT   = 40;

__device__ __forceinline__ float bf2f(unsigned short u) {
  return __uint_as_float(((unsigned)u) << 16);
}
__device__ __forceinline__ unsigned short f2bf(float f) {
  unsigned x = __float_as_uint(f);
  x += 0x7FFFu + ((x >> 16) & 1u);      // RNE
  return (unsigned short)(x >> 16);
}

// flagged scalar load: input array is fp32 (isf32!=0) or bf16
__device__ __forceinline__ float ldflex(const void* p, size_t i, int isf32) {
  return isf32 ? ((const float*)p)[i] : bf2f(((const unsigned short*)p)[i]);
}

// JAX threefry2x32, key=(0,42), PARTITIONABLE counter scheme (default since
// JAX 0.4.30): element i uses pair (hi32(i), lo32(i)) = (0, i); 32-bit output
// is x0_final ^ x1_final.  keep  <=>  bit31(bits) == 0  (uniform u < 0.5).
__device__ __forceinline__ unsigned tf_rotl(unsigned x, int d) {
  return (x << d) | (x >> (32 - d));
}
__device__ unsigned threefry_bits(unsigned i) {
  const unsigned k0 = 0u, k1 = 42u, k2 = 0x1BD11BDAu ^ 0u ^ 42u;
  unsigned x0 = 0u + k0, x1 = i + k1;
#define TF_R(r) { x0 += x1; x1 = tf_rotl(x1, (r)) ^ x0; }
  TF_R(13) TF_R(15) TF_R(26) TF_R(6)   x0 += k1; x1 += k2 + 1u;
  TF_R(17) TF_R(29) TF_R(16) TF_R(24)  x0 += k2; x1 += k0 + 2u;
  TF_R(13) TF_R(15) TF_R(26) TF_R(6)   x0 += k0; x1 += k1 + 3u;
  TF_R(17) TF_R(29) TF_R(16) TF_R(24)  x0 += k1; x1 += k2 + 4u;
  TF_R(13) TF_R(15) TF_R(26) TF_R(6)   x0 += k2; x1 += k0 + 5u;
#undef TF_R
  return x0 ^ x1;
}

// ---------------- dtype detect ----------------
__global__ void k_detect(const unsigned short* __restrict__ x, int* __restrict__ flag) {
  __shared__ int cnt;
  if (threadIdx.x == 0) cnt = 0;
  __syncthreads();
  int c = 0;
  for (int i = threadIdx.x; i < 2048; i += 256) {
    unsigned e = (x[i] >> 7) & 0xFFu;
    if (e >= 0xC0u) c++;
  }
  atomicAdd(&cnt, c);
  __syncthreads();
  if (threadIdx.x == 0) flag[0] = (cnt >= 64) ? 1 : 0;
}

__global__ void k_zero(int* __restrict__ p, int n) {
  int i = blockIdx.x * 256 + threadIdx.x;
  if (i < n) p[i] = 0;
}

// ---------------- CSR build ----------------
__global__ void k_hist(const int* __restrict__ dst, int* __restrict__ deg, int E) {
  int e = blockIdx.x * 256 + threadIdx.x;
  if (e < E) atomicAdd(&deg[dst[e]], 1);
}

__global__ void k_scan(int* __restrict__ deg, int* __restrict__ offs) {
  __shared__ int part[1024];
  int t = threadIdx.x;
  int begin = t * 49;
  int end = begin + 49; if (end > N_NODES) end = N_NODES;
  int s = 0;
  for (int i = begin; i < end; ++i) s += deg[i];
  part[t] = s;
  __syncthreads();
  for (int off = 1; off < 1024; off <<= 1) {
    int x = (t >= off) ? part[t - off] : 0;
    __syncthreads();
    part[t] += x;
    __syncthreads();
  }
  int run = part[t] - s;
  for (int i = begin; i < end; ++i) {
    int d = deg[i];
    offs[i] = run;
    run += d;
    deg[i] = 0;                          // becomes scatter cursor
  }
  if (t == 1023) offs[N_NODES] = part[1023];
}

// packed edge: (src << 16) | bf16(weight)   — src < 50000 < 2^16
__global__ void k_scatter(const int* __restrict__ src, const int* __restrict__ dst,
                          const void* __restrict__ w,
                          const int* __restrict__ offs, int* __restrict__ cursor,
                          unsigned* __restrict__ ep,
                          const int* __restrict__ flag, int E) {
  int isf32 = flag[0];
  int e = blockIdx.x * 256 + threadIdx.x;
  if (e < E) {
    int d = dst[e];
    int pos = offs[d] + atomicAdd(&cursor[d], 1);
    if (pos >= 0 && pos < E)
      ep[pos] = ((unsigned)src[e] << 16) | (unsigned)f2bf(ldflex(w, e, isf32));
  }
}

// ---------------- layer-1 GEMM halves: h1h = x @ W1[:, half*128 .. +128) ------
__global__ __launch_bounds__(256) void k_gemm1h(const void* __restrict__ X,
                                                const void* __restrict__ W,
                                                unsigned short* __restrict__ h1h,
                                                const int* __restrict__ flag, int half) {
  __shared__ float xs[16][F_IN];
  int isf32 = flag[0];
  int t = threadIdx.x;
  int r0 = blockIdx.x * 16;
  for (int i = t; i < 16 * F_IN; i += 256) {
    int rr = i >> 9, kk = i & 511;
    xs[rr][kk] = ldflex(X, (size_t)(r0 + rr) * F_IN + kk, isf32);
  }
  __syncthreads();
  int col = t & 127;
  int rblk = (t >> 7) * 8;
  float acc[8] = {0.f, 0.f, 0.f, 0.f, 0.f, 0.f, 0.f, 0.f};
  for (int k = 0; k < F_IN; ++k) {
    float w = ldflex(W, (size_t)k * F_HID + half * 128 + col, isf32);
#pragma unroll
    for (int j = 0; j < 8; ++j) acc[j] = fmaf(xs[rblk + j][k], w, acc[j]);
  }
#pragma unroll
  for (int j = 0; j < 8; ++j)
    h1h[(size_t)(r0 + rblk + j) * 128 + col] = f2bf(acc[j]);
}

// ---------------- fused agg1-half + gemm2-half (o1 accumulates) ---------------
__global__ __launch_bounds__(256) void k_agg1h(const ushort2* __restrict__ h1h2,
                                               const int* __restrict__ offs,
                                               const unsigned* __restrict__ ep,
                                               const void* __restrict__ b1,
                                               const void* __restrict__ W2,
                                               float* __restrict__ o1,
                                               const int* __restrict__ flag, int half) {
  __shared__ unsigned short w2h[128 * F_OUT];
  __shared__ float hrow[4][128];
  int isf32 = flag[0];
  int t = threadIdx.x;
  for (int i = t; i < 128 * F_OUT; i += 256) {
    int k = i / F_OUT, j = i - k * F_OUT;
    w2h[i] = f2bf(ldflex(W2, (size_t)(half * 128 + k) * F_OUT + j, isf32));
  }
  int wave = t >> 6, lane = t & 63;
  int wid = blockIdx.x * 4 + wave;
  int s0 = offs[wid], s1 = offs[wid + 1];
  float a0 = 0.f, a1 = 0.f;
  for (int e = s0; e < s1; ++e) {
    unsigned pe = ep[e];
    int src = pe >> 16;
    float w = bf2f((unsigned short)(pe & 0xFFFFu));
    ushort2 v = h1h2[(size_t)src * 64 + lane];
    a0 = fmaf(w, bf2f(v.x), a0);
    a1 = fmaf(w, bf2f(v.y), a1);
  }
  int c0 = lane * 2;
  int gc = half * 128 + c0;
  float r0 = fmaxf(a0 + ldflex(b1, gc + 0, isf32), 0.f);
  float r1 = fmaxf(a1 + ldflex(b1, gc + 1, isf32), 0.f);
  unsigned base = (unsigned)wid * 256u + (unsigned)gc;
  r0 = (threefry_bits(base + 0u) >> 31) ? 0.f : r0 * 2.f;   // keep iff u<0.5
  r1 = (threefry_bits(base + 1u) >> 31) ? 0.f : r1 * 2.f;
  hrow[wave][c0 + 0] = r0;
  hrow[wave][c0 + 1] = r1;
  __syncthreads();
  if (lane < F_OUT) {
    float acc = 0.f;
#pragma unroll 8
    for (int k = 0; k < 128; ++k)
      acc = fmaf(hrow[wave][k], bf2f(w2h[k * F_OUT + lane]), acc);
    o1[(size_t)wid * F_OUT + lane] += acc;
  }
}

// ---------------- agg2: out[d] = sum_e w*o1[src] + b2 (fp32 out) --------------
__global__ __launch_bounds__(256) void k_agg2(const float* __restrict__ o1,
                                              const int* __restrict__ offs,
                                              const unsigned* __restrict__ ep,
                                              const void* __restrict__ b2,
                                              float* __restrict__ out,
                                              const int* __restrict__ flag) {
  int isf32 = flag[0];
  int wid  = (blockIdx.x << 2) + (threadIdx.x >> 6);
  int lane = threadIdx.x & 63;
  if (lane >= F_OUT) return;
  int s0 = offs[wid], s1 = offs[wid + 1];
  float acc = 0.f;
  for (int e = s0; e < s1; ++e) {
    unsigned pe = ep[e];
    int src = pe >> 16;
    float w = bf2f((unsigned short)(pe & 0xFFFFu));
    acc = fmaf(w, o1[(size_t)src * F_OUT + lane], acc);
  }
  out[(size_t)wid * F_OUT + lane] = acc + ldflex(b2, lane, isf32);
}

extern "C" void kernel_launch(void* const* d_in, const int* in_sizes, int n_in,
                              void* d_out, int out_size, void* d_ws, size_t ws_size,
                              hipStream_t stream) {
  const void* x    = d_in[0];
  const int*  esrc = (const int*)d_in[1];
  const int*  edst = (const int*)d_in[2];
  const void* ew   = d_in[3];
  const void* W1   = d_in[4];
  const void* b1   = d_in[5];
  const void* W2   = d_in[6];
  const void* b2   = d_in[7];
  const int E = in_sizes[1];

  // workspace: ~27.6 MB (verified < ws_size via round-7 beacon)
  char* p = (char*)d_ws;
  auto alloc = [&](size_t bytes) { char* r = p; p += (bytes + 255) & ~(size_t)255; return r; };
  int*            flag = (int*)alloc(256);
  unsigned short* h1h  = (unsigned short*)alloc((size_t)N_NODES * 128 * 2);
  float*          o1   = (float*)alloc((size_t)N_NODES * F_OUT * 4);
  unsigned*       ep   = (unsigned*)alloc((size_t)E * 4);
  int*            offs = (int*)alloc((size_t)(N_NODES + 1) * 4);
  int*            deg  = (int*)alloc((size_t)N_NODES * 4);

  int eb = (E + 255) / 256;
  k_detect<<<1, 256, 0, stream>>>((const unsigned short*)x, flag);
  k_zero<<<(N_NODES + 255) / 256, 256, 0, stream>>>(deg, N_NODES);
  k_zero<<<(N_NODES * F_OUT + 255) / 256, 256, 0, stream>>>((int*)o1, N_NODES * F_OUT);
  k_hist<<<eb, 256, 0, stream>>>(edst, deg, E);
  k_scan<<<1, 1024, 0, stream>>>(deg, offs);
  k_scatter<<<eb, 256, 0, stream>>>(esrc, edst, ew, offs, deg, ep, flag, E);

  for (int half = 0; half < 2; ++half) {
    k_gemm1h<<<N_NODES / 16, 256, 0, stream>>>(x, W1, h1h, flag, half);
    k_agg1h<<<N_NODES / 4, 256, 0, stream>>>((const ushort2*)h1h, offs, ep, b1, W2, o1, flag, half);
  }
  k_agg2<<<N_NODES / 4, 256, 0, stream>>>(o1, offs, ep, b2, (float*)d_out, flag);
}

// Round 9
// 830.265 us; speedup vs baseline: 1.8062x; 1.8062x over previous
//
#include <hip/hip_runtime.h>

typedef short bf16x8 __attribute__((ext_vector_type(8)));
typedef float f32x4 __attribute__((ext_vector_type(4)));

constexpr int N_NODES = 50000;
constexpr int F_IN    = 512;
constexpr int F_HID   = 256;
constexpr int F_OUT   = 40;

__device__ __forceinline__ float bf2f(unsigned short u) {
  return __uint_as_float(((unsigned)u) << 16);
}
__device__ __forceinline__ unsigned short f2bf(float f) {
  unsigned x = __float_as_uint(f);
  x += 0x7FFFu + ((x >> 16) & 1u);      // RNE
  return (unsigned short)(x >> 16);
}

// JAX threefry2x32, key=(0,42), PARTITIONABLE counter scheme (verified R8):
// element i -> pair (0, i); output = x0_final ^ x1_final; keep iff bit31==0.
__device__ __forceinline__ unsigned tf_rotl(unsigned x, int d) {
  return (x << d) | (x >> (32 - d));
}
__device__ __forceinline__ unsigned threefry_bits(unsigned i) {
  const unsigned k0 = 0u, k1 = 42u, k2 = 0x1BD11BDAu ^ 0u ^ 42u;
  unsigned x0 = 0u + k0, x1 = i + k1;
#define TF_R(r) { x0 += x1; x1 = tf_rotl(x1, (r)) ^ x0; }
  TF_R(13) TF_R(15) TF_R(26) TF_R(6)   x0 += k1; x1 += k2 + 1u;
  TF_R(17) TF_R(29) TF_R(16) TF_R(24)  x0 += k2; x1 += k0 + 2u;
  TF_R(13) TF_R(15) TF_R(26) TF_R(6)   x0 += k0; x1 += k1 + 3u;
  TF_R(17) TF_R(29) TF_R(16) TF_R(24)  x0 += k1; x1 += k2 + 4u;
  TF_R(13) TF_R(15) TF_R(26) TF_R(6)   x0 += k2; x1 += k0 + 5u;
#undef TF_R
  return x0 ^ x1;
}

__global__ void k_zero(int* __restrict__ p, int n) {
  int i = blockIdx.x * 256 + threadIdx.x;
  if (i < n) p[i] = 0;
}

// ---------------- CSR build ----------------
__global__ void k_hist(const int* __restrict__ dst, int* __restrict__ deg, int E) {
  int e = blockIdx.x * 256 + threadIdx.x;
  if (e < E) atomicAdd(&deg[dst[e]], 1);
}

__global__ void k_scan(int* __restrict__ deg, int* __restrict__ offs) {
  __shared__ int part[1024];
  int t = threadIdx.x;
  int begin = t * 49;
  int end = begin + 49; if (end > N_NODES) end = N_NODES;
  int s = 0;
  for (int i = begin; i < end; ++i) s += deg[i];
  part[t] = s;
  __syncthreads();
  for (int off = 1; off < 1024; off <<= 1) {
    int x = (t >= off) ? part[t - off] : 0;
    __syncthreads();
    part[t] += x;
    __syncthreads();
  }
  int run = part[t] - s;
  for (int i = begin; i < end; ++i) {
    int d = deg[i];
    offs[i] = run;
    run += d;
    deg[i] = 0;                          // becomes scatter cursor
  }
  if (t == 1023) offs[N_NODES] = part[1023];
}

// packed edge: (src << 16) | bf16(weight)
__global__ void k_scatter(const int* __restrict__ src, const int* __restrict__ dst,
                          const float* __restrict__ w,
                          const int* __restrict__ offs, int* __restrict__ cursor,
                          unsigned* __restrict__ ep, int E) {
  int e = blockIdx.x * 256 + threadIdx.x;
  if (e < E) {
    int d = dst[e];
    int pos = offs[d] + atomicAdd(&cursor[d], 1);
    if (pos >= 0 && pos < E)
      ep[pos] = ((unsigned)src[e] << 16) | (unsigned)f2bf(w[e]);
  }
}

// ---------------- W1 -> bf16 transpose: wT[c][k] = bf16(W1[k][c]) -------------
__global__ void k_wt(const float* __restrict__ W1, unsigned short* __restrict__ wT) {
  int i = blockIdx.x * 256 + threadIdx.x;      // 131072 elements
  if (i < F_IN * F_HID) {
    int c = i >> 9, k = i & 511;
    wT[i] = f2bf(W1[(size_t)k * F_HID + c]);
  }
}

// ---------------- layer-1 MFMA GEMM half: h1h = x @ W1[:, half*128 .. +128) ---
// block 256 (4 waves), tile M=64 x N=128, K-step 64 (2 MFMA chunks of 32).
// Wave w: rows [w*16, +16), all 128 cols (8 n-tiles). A staged bf16 in LDS
// (each x elem converted once); B frags loaded straight from L2-resident wT.
__global__ __launch_bounds__(256) void k_gemm1m(const float* __restrict__ X,
                                                const unsigned short* __restrict__ wT,
                                                unsigned short* __restrict__ h1h,
                                                int half) {
  __shared__ unsigned short xs[64][72];        // pad 72: 16B-aligned rows, 2-way banks
  int t = threadIdx.x;
  int wave = t >> 6, lane = t & 63, q = lane >> 4, r = lane & 15;
  int r0 = blockIdx.x * 64;
  const unsigned short* wbase = wT + (size_t)half * 128 * F_IN;
  f32x4 acc[8];
#pragma unroll
  for (int n = 0; n < 8; ++n) acc[n] = (f32x4){0.f, 0.f, 0.f, 0.f};

  for (int k0 = 0; k0 < F_IN; k0 += 64) {
    __syncthreads();                           // xs reuse guard
#pragma unroll
    for (int i = t; i < 64 * 64; i += 256) {
      int rr = i >> 6, kk = i & 63;
      int row = r0 + rr; if (row > N_NODES - 1) row = N_NODES - 1;
      xs[rr][kk] = f2bf(X[(size_t)row * F_IN + k0 + kk]);
    }
    __syncthreads();
#pragma unroll
    for (int kc = 0; kc < 2; ++kc) {
      bf16x8 a = *(const bf16x8*)&xs[wave * 16 + r][kc * 32 + q * 8];
#pragma unroll
      for (int n = 0; n < 8; ++n) {
        bf16x8 b = *(const bf16x8*)(wbase + (size_t)(n * 16 + r) * F_IN + k0 + kc * 32 + q * 8);
        acc[n] = __builtin_amdgcn_mfma_f32_16x16x32_bf16(a, b, acc[n], 0, 0, 0);
      }
    }
  }
  // D: col = n*16 + r, row = wave*16 + q*4 + tt  (verified layout)
  int mrow = r0 + wave * 16 + q * 4;
#pragma unroll
  for (int n = 0; n < 8; ++n) {
#pragma unroll
    for (int tt = 0; tt < 4; ++tt) {
      int row = mrow + tt;
      if (row < N_NODES) h1h[(size_t)row * 128 + n * 16 + r] = f2bf(acc[n][tt]);
    }
  }
}

// ---------------- fused agg1-half + gemm2-half (o1 accumulates) ---------------
// Edge loop unrolled x4: 4 ep loads + 4 gathers in flight (MLP).
__global__ __launch_bounds__(256) void k_agg1h(const ushort2* __restrict__ h1h2,
                                               const int* __restrict__ offs,
                                               const unsigned* __restrict__ ep,
                                               const float* __restrict__ b1,
                                               const float* __restrict__ W2,
                                               float* __restrict__ o1, int half) {
  __shared__ unsigned short w2h[128 * F_OUT];  // 10 KB
  __shared__ float hrow[4][128];               // 2 KB
  int t = threadIdx.x;
  for (int i = t; i < 128 * F_OUT; i += 256) {
    int k = i / F_OUT, j = i - k * F_OUT;
    w2h[i] = f2bf(W2[(size_t)(half * 128 + k) * F_OUT + j]);
  }
  int wave = t >> 6, lane = t & 63;
  int wid = blockIdx.x * 4 + wave;
  int s0 = offs[wid], s1 = offs[wid + 1];
  float a0 = 0.f, a1 = 0.f;
  int e = s0;
  for (; e + 4 <= s1; e += 4) {
    unsigned p0 = ep[e], p1 = ep[e + 1], p2 = ep[e + 2], p3 = ep[e + 3];
    ushort2 v0 = h1h2[(size_t)(p0 >> 16) * 64 + lane];
    ushort2 v1 = h1h2[(size_t)(p1 >> 16) * 64 + lane];
    ushort2 v2 = h1h2[(size_t)(p2 >> 16) * 64 + lane];
    ushort2 v3 = h1h2[(size_t)(p3 >> 16) * 64 + lane];
    float w0 = bf2f((unsigned short)p0), w1 = bf2f((unsigned short)p1);
    float w2 = bf2f((unsigned short)p2), w3 = bf2f((unsigned short)p3);
    a0 = fmaf(w0, bf2f(v0.x), a0); a1 = fmaf(w0, bf2f(v0.y), a1);
    a0 = fmaf(w1, bf2f(v1.x), a0); a1 = fmaf(w1, bf2f(v1.y), a1);
    a0 = fmaf(w2, bf2f(v2.x), a0); a1 = fmaf(w2, bf2f(v2.y), a1);
    a0 = fmaf(w3, bf2f(v3.x), a0); a1 = fmaf(w3, bf2f(v3.y), a1);
  }
  for (; e < s1; ++e) {
    unsigned pe = ep[e];
    float w = bf2f((unsigned short)pe);
    ushort2 v = h1h2[(size_t)(pe >> 16) * 64 + lane];
    a0 = fmaf(w, bf2f(v.x), a0);
    a1 = fmaf(w, bf2f(v.y), a1);
  }
  int c0 = lane * 2;
  int gc = half * 128 + c0;
  float r0 = fmaxf(a0 + b1[gc + 0], 0.f);
  float r1 = fmaxf(a1 + b1[gc + 1], 0.f);
  unsigned base = (unsigned)wid * 256u + (unsigned)gc;
  r0 = (threefry_bits(base + 0u) >> 31) ? 0.f : r0 * 2.f;   // keep iff u<0.5
  r1 = (threefry_bits(base + 1u) >> 31) ? 0.f : r1 * 2.f;
  hrow[wave][c0 + 0] = r0;
  hrow[wave][c0 + 1] = r1;
  __syncthreads();                             // w2h + hrow visibility
  if (lane < F_OUT) {
    float acc = 0.f;
#pragma unroll 8
    for (int k = 0; k < 128; ++k)
      acc = fmaf(hrow[wave][k], bf2f(w2h[k * F_OUT + lane]), acc);
    o1[(size_t)wid * F_OUT + lane] += acc;
  }
}

// ---------------- agg2: out[d] = sum_e w*o1[src] + b2 (fp32 out) --------------
__global__ __launch_bounds__(256) void k_agg2(const float* __restrict__ o1,
                                              const int* __restrict__ offs,
                                              const unsigned* __restrict__ ep,
                                              const float* __restrict__ b2,
                                              float* __restrict__ out) {
  int wid  = (blockIdx.x << 2) + (threadIdx.x >> 6);
  int lane = threadIdx.x & 63;
  if (lane >= F_OUT) return;
  int s0 = offs[wid], s1 = offs[wid + 1];
  float acc = 0.f;
  int e = s0;
  for (; e + 4 <= s1; e += 4) {
    unsigned p0 = ep[e], p1 = ep[e + 1], p2 = ep[e + 2], p3 = ep[e + 3];
    float g0 = o1[(size_t)(p0 >> 16) * F_OUT + lane];
    float g1 = o1[(size_t)(p1 >> 16) * F_OUT + lane];
    float g2 = o1[(size_t)(p2 >> 16) * F_OUT + lane];
    float g3 = o1[(size_t)(p3 >> 16) * F_OUT + lane];
    acc = fmaf(bf2f((unsigned short)p0), g0, acc);
    acc = fmaf(bf2f((unsigned short)p1), g1, acc);
    acc = fmaf(bf2f((unsigned short)p2), g2, acc);
    acc = fmaf(bf2f((unsigned short)p3), g3, acc);
  }
  for (; e < s1; ++e) {
    unsigned pe = ep[e];
    acc = fmaf(bf2f((unsigned short)pe), o1[(size_t)(pe >> 16) * F_OUT + lane], acc);
  }
  out[(size_t)wid * F_OUT + lane] = acc + b2[lane];
}

extern "C" void kernel_launch(void* const* d_in, const int* in_sizes, int n_in,
                              void* d_out, int out_size, void* d_ws, size_t ws_size,
                              hipStream_t stream) {
  const float* x    = (const float*)d_in[0];
  const int*   esrc = (const int*)d_in[1];
  const int*   edst = (const int*)d_in[2];
  const float* ew   = (const float*)d_in[3];
  const float* W1   = (const float*)d_in[4];
  const float* b1   = (const float*)d_in[5];
  const float* W2   = (const float*)d_in[6];
  const float* b2   = (const float*)d_in[7];
  const int E = in_sizes[1];

  // workspace ~27.9 MB (<= verified budget)
  char* p = (char*)d_ws;
  auto alloc = [&](size_t bytes) { char* r = p; p += (bytes + 255) & ~(size_t)255; return r; };
  unsigned short* h1h  = (unsigned short*)alloc((size_t)N_NODES * 128 * 2); // 12.8 MB
  float*          o1   = (float*)alloc((size_t)N_NODES * F_OUT * 4);        // 8 MB
  unsigned*       ep   = (unsigned*)alloc((size_t)E * 4);                   // 6.4 MB
  unsigned short* wT   = (unsigned short*)alloc((size_t)F_IN * F_HID * 2);  // 262 KB
  int*            offs = (int*)alloc((size_t)(N_NODES + 1) * 4);
  int*            deg  = (int*)alloc((size_t)N_NODES * 4);

  int eb = (E + 255) / 256;
  k_zero<<<(N_NODES + 255) / 256, 256, 0, stream>>>(deg, N_NODES);
  k_zero<<<(N_NODES * F_OUT + 255) / 256, 256, 0, stream>>>((int*)o1, N_NODES * F_OUT);
  k_wt<<<(F_IN * F_HID + 255) / 256, 256, 0, stream>>>(W1, wT);
  k_hist<<<eb, 256, 0, stream>>>(edst, deg, E);
  k_scan<<<1, 1024, 0, stream>>>(deg, offs);
  k_scatter<<<eb, 256, 0, stream>>>(esrc, edst, ew, offs, deg, ep, E);

  int gblocks = (N_NODES + 63) / 64;           // 782
  for (int half = 0; half < 2; ++half) {
    k_gemm1m<<<gblocks, 256, 0, stream>>>(x, wT, h1h, half);
    k_agg1h<<<N_NODES / 4, 256, 0, stream>>>((const ushort2*)h1h, offs, ep, b1, W2, o1, half);
  }
  k_agg2<<<N_NODES / 4, 256, 0, stream>>>(o1, offs, ep, b2, (float*)d_out);
}